// Round 4
// baseline (535.221 us; speedup 1.0000x reference)
//
#include <hip/hip_runtime.h>
#include <math.h>

// Problem constants
#define D_FEAT 8192
#define NC4    2048          // float4 columns per R row
#define T_RES  2048
#define LORD   16

// Geometry: 256 blocks x 512 threads (1 block/CU). ROW-OWNERSHIP layout:
// thread h holds rows 4h..4h+3 of the block's 32-column slab (cols bid*32..):
// rr[4][8] float4 = 128 VGPRs. u[t] for the slab is computed entirely in-lane
// (no shuffles); y needs one cross-lane reduce (value-halving exchange).
#define NTHR 512
#define NBLK 256
#define CH   32              // rows per reduction chunk
#define NOWN 64              // chunk owners (64 x 32 = 2048 rows)
#define NREPA 8              // A-flag replicas (pollers = 64 owners)
#define NREPB 16             // B-flag replicas (pollers = 256 blocks)
#define UPSLOT (NBLK*T_RES)  // 524288 floats = 2MB per u-partial slot

// ---- Global workspace layout (float offsets) ----
// Zeroed region (~166 KB memset per launch): coef + flags.
#define G_COEF  0                              // 16
#define G_FUPA  16                             // 17 x NREPA x 256 partial-ready
#define G_FREDB (G_FUPA + 17*NREPA*256)        // 17 x NREPB u64 masks (line-pad)
#define G_FCOEF (G_FREDB + 17*NREPB*16)        // NREPB x 16 (1 word per line)
#define G_FNUM  (G_FCOEF + NREPB*16)           // NREPA x 256 (block 0 polls)
#define G_ZEND  (G_FNUM + NREPA*256)
// Rotated single-write-then-single-read regions (cached reads safe: caches
// invalidated at dispatch; each slot written once then read once per launch):
#define G_URAW  G_ZEND                         // 17 x 2048 reduced u (slot16 = Rf)
#define G_UUP   (G_URAW + 17*2048)             // 64 |u_init|^2 owner partials
#define G_FFP   (G_UUP + 64)                   // 256 f.f partials
#define G_B2P   (G_FFP + 256)                  // 16 x 256 b2 partials (slot j)
#define G_DP    (G_B2P + 16*256)               // 16 x 16 x 64 dot owner partials
#define G_NUMP  (G_DP + 16*16*64)              // 16 x 256
#define G_DENP  (G_NUMP + 16*256)              // 16 x 256
#define G_UPB   ((G_DENP + 16*256 + 1023) & ~1023)  // 17 x UPSLOT u partials

// ---- MALL-coherent uncached ops (writes + sync polling) — validated R5-R8
__device__ __forceinline__ void astore(float* p, float v) {
    __hip_atomic_store(p, v, __ATOMIC_RELAXED, __HIP_MEMORY_SCOPE_AGENT);
}
__device__ __forceinline__ void astore64(unsigned long long* p, unsigned long long v) {
    __hip_atomic_store(p, v, __ATOMIC_RELAXED, __HIP_MEMORY_SCOPE_AGENT);
}
__device__ __forceinline__ void astoreu(unsigned* p, unsigned v) {
    __hip_atomic_store(p, v, __ATOMIC_RELAXED, __HIP_MEMORY_SCOPE_AGENT);
}
__device__ __forceinline__ unsigned aloadu(const unsigned* p) {
    return __hip_atomic_load(p, __ATOMIC_RELAXED, __HIP_MEMORY_SCOPE_AGENT);
}
__device__ __forceinline__ unsigned long long aload64(const unsigned long long* p) {
    return __hip_atomic_load(p, __ATOMIC_RELAXED, __HIP_MEMORY_SCOPE_AGENT);
}

// Sync A (all 256 produce u partials; 64 owners consume): __syncthreads drains
// vmcnt so payload astores are at MALL before the flag stores issue.
__device__ __forceinline__ void sigA(unsigned* fl, int bid) {
    __syncthreads();
    if (threadIdx.x < NREPA) astoreu(&fl[threadIdx.x*256 + bid], 1u);
}
// Owners poll replica (bid&7): 8 owner-blocks x 64 lanes per replica — low
// fan-in (R1 lesson: high poller fan-in saturates the fabric).
__device__ __forceinline__ void pollA(const unsigned* fl, int bid) {
    if (threadIdx.x < 64) {
        const unsigned* p = fl + (bid & (NREPA-1))*256 + 4*threadIdx.x;
        for (;;) {
            unsigned a = aloadu(p) & aloadu(p+1) & aloadu(p+2) & aloadu(p+3);
            if (__all((int)a)) break;
            __builtin_amdgcn_s_sleep(2);
        }
    }
    __syncthreads();
}

// Sync B (64 owners produce reduced u; all 256 consume): owners atomic-or
// their bit into NREPB replicated u64 masks (one per 64B line). Each consumer
// polls ONE word of replica (bid&15) -> 16 blocks x 1 lane per line.
__device__ __forceinline__ void sigB(unsigned* fl, int bid) {
    __syncthreads();   // drain reduced-u / DP / UUP stores
    if (threadIdx.x < NREPB)
        __hip_atomic_fetch_or((unsigned long long*)(fl + threadIdx.x*16),
                              1ULL << bid, __ATOMIC_RELAXED,
                              __HIP_MEMORY_SCOPE_AGENT);
}
__device__ __forceinline__ void pollB(const unsigned* fl, int bid) {
    if (threadIdx.x == 0)
        while (aload64((const unsigned long long*)(fl + (bid & (NREPB-1))*16))
               != 0xFFFFFFFFFFFFFFFFULL)
            __builtin_amdgcn_s_sleep(2);
    __syncthreads();
}

__device__ __forceinline__ float wave_sum64(float s) {
    #pragma unroll
    for (int m = 1; m < 64; m <<= 1) s += __shfl_xor(s, m, 64);
    return s;
}
// Sum over lanes 0..31 (m<32 keeps halves independent; lane 0 result valid).
__device__ __forceinline__ float sum32(float s) {
    #pragma unroll
    for (int m = 1; m < 32; m <<= 1) s += __shfl_xor(s, m, 64);
    return s;
}

__device__ __forceinline__ float4 f4add(float4 a, float4 b) {
    return make_float4(a.x+b.x, a.y+b.y, a.z+b.z, a.w+b.w);
}
__device__ __forceinline__ float4 f4shfl_xor(float4 v, int m) {
    float4 r;
    r.x = __shfl_xor(v.x, m, 64); r.y = __shfl_xor(v.y, m, 64);
    r.z = __shfl_xor(v.z, m, 64); r.w = __shfl_xor(v.w, m, 64);
    return r;
}

// u slab pass, row-ownership: u[4h+r] = R[4h+r][slab] . w_slab, fully in-lane.
// w read as 8 float4 LDS broadcasts (conflict-free). Fixed pairwise tree.
__device__ __forceinline__ void u_pass_row(const float4 (&rr)[4][8],
                                           const float* wsl, float (&out)[4]) {
    float4 w4[8];
    #pragma unroll
    for (int c = 0; c < 8; ++c) w4[c] = ((const float4*)wsl)[c];
    #pragma unroll
    for (int r = 0; r < 4; ++r) {
        float d0 = rr[r][0].x*w4[0].x + rr[r][0].y*w4[0].y + rr[r][0].z*w4[0].z + rr[r][0].w*w4[0].w;
        float d1 = rr[r][1].x*w4[1].x + rr[r][1].y*w4[1].y + rr[r][1].z*w4[1].z + rr[r][1].w*w4[1].w;
        float d2 = rr[r][2].x*w4[2].x + rr[r][2].y*w4[2].y + rr[r][2].z*w4[2].z + rr[r][2].w*w4[2].w;
        float d3 = rr[r][3].x*w4[3].x + rr[r][3].y*w4[3].y + rr[r][3].z*w4[3].z + rr[r][3].w*w4[3].w;
        float d4 = rr[r][4].x*w4[4].x + rr[r][4].y*w4[4].y + rr[r][4].z*w4[4].z + rr[r][4].w*w4[4].w;
        float d5 = rr[r][5].x*w4[5].x + rr[r][5].y*w4[5].y + rr[r][5].z*w4[5].z + rr[r][5].w*w4[5].w;
        float d6 = rr[r][6].x*w4[6].x + rr[r][6].y*w4[6].y + rr[r][6].z*w4[6].z + rr[r][6].w*w4[6].w;
        float d7 = rr[r][7].x*w4[7].x + rr[r][7].y*w4[7].y + rr[r][7].z*w4[7].z + rr[r][7].w*w4[7].w;
        out[r] = ((d0+d1)+(d2+d3)) + ((d4+d5)+(d6+d7));
    }
}

// Flush 4 u values, chunk layout UP[t>>5][bid][t&31]: 16B contiguous per
// thread, wave covers 8 full 128B runs -> full-line write packets.
__device__ __forceinline__ void flush4(float* UP, const float (&out)[4],
                                       int h, int bid) {
    const int t0 = h << 2;
    float* dst = &UP[(size_t)(t0 >> 5)*(NBLK*CH) + bid*CH + (t0 & 31)];
    unsigned long long p0, p1;
    __builtin_memcpy(&p0, &out[0], 8);
    __builtin_memcpy(&p1, &out[2], 8);
    astore64((unsigned long long*)dst, p0);
    astore64((unsigned long long*)(dst + 2), p1);
}

// Reduce acc[8] (32 col partials per lane) across the block into ysl[32].
// Value-halving exchange: level m keeps low/high half of the remaining col
// range by lane bit; ~40 wave-ops total. Deterministic fixed tree.
__device__ __forceinline__ void y_reduce8(const float4 (&acc)[8],
                                          float (*red)[8][4], float* ysl,
                                          int wave, int lane, int tid) {
    const bool b0 = lane & 1, b1 = lane & 2, b2 = lane & 4;
    float4 h0_0, h0_1, h0_2, h0_3;
    {
        float4 s0 = b0 ? acc[0] : acc[4];
        float4 s1 = b0 ? acc[1] : acc[5];
        float4 s2 = b0 ? acc[2] : acc[6];
        float4 s3 = b0 ? acc[3] : acc[7];
        float4 r0 = f4shfl_xor(s0, 1), r1 = f4shfl_xor(s1, 1);
        float4 r2 = f4shfl_xor(s2, 1), r3 = f4shfl_xor(s3, 1);
        h0_0 = f4add(b0 ? acc[4] : acc[0], r0);
        h0_1 = f4add(b0 ? acc[5] : acc[1], r1);
        h0_2 = f4add(b0 ? acc[6] : acc[2], r2);
        h0_3 = f4add(b0 ? acc[7] : acc[3], r3);
    }
    float4 h1_0, h1_1;
    {
        float4 s0 = b1 ? h1_0 : h0_2;   // placeholder fixed below
        (void)s0;
        float4 t0 = b1 ? h0_0 : h0_2;
        float4 t1 = b1 ? h0_1 : h0_3;
        float4 r0 = f4shfl_xor(t0, 2), r1 = f4shfl_xor(t1, 2);
        h1_0 = f4add(b1 ? h0_2 : h0_0, r0);
        h1_1 = f4add(b1 ? h0_3 : h0_1, r1);
    }
    float4 h2;
    {
        float4 t0 = b2 ? h1_0 : h1_1;
        float4 r0 = f4shfl_xor(t0, 4);
        h2 = f4add(b2 ? h1_1 : h1_0, r0);
    }
    h2 = f4add(h2, f4shfl_xor(h2, 8));
    h2 = f4add(h2, f4shfl_xor(h2, 16));
    h2 = f4add(h2, f4shfl_xor(h2, 32));
    if (lane < 8) {
        const int G = ((lane & 1) << 2) | (lane & 2) | ((lane >> 2) & 1);
        red[wave][G][0] = h2.x; red[wave][G][1] = h2.y;
        red[wave][G][2] = h2.z; red[wave][G][3] = h2.w;
    }
    __syncthreads();
    if (tid < 32) {
        const int g = tid >> 2, comp = tid & 3;
        float s = 0.f;
        #pragma unroll
        for (int w = 0; w < 8; ++w) s += red[w][g][comp];
        ysl[g*4 + comp] = s;
    }
    __syncthreads();
}

__global__ __launch_bounds__(NTHR, 2) void k_all(
    const float* __restrict__ Rm, const float* __restrict__ f,
    const float* __restrict__ Dm, float* __restrict__ out,
    float* __restrict__ ws)
{
    __shared__ float red[8][8][4];
    __shared__ float red2[32][17];
    __shared__ float ufin32[32];
    __shared__ float uh[17][32];       // owner-only: chunk history for dots
    __shared__ __align__(16) float ysl[32];
    __shared__ __align__(16) float dirs[32];
    __shared__ __align__(16) float fsl[32];
    __shared__ __align__(16) float Wh[LORD][32];
    __shared__ float bh[LORD];
    __shared__ float alph[LORD];
    __shared__ float dotl[LORD];
    __shared__ float cf[LORD];
    __shared__ float misc[4];   // [0]=b2j  [2]=ff  [3]=uu

    float* coefg    = ws + G_COEF;
    unsigned* fupA  = (unsigned*)(ws + G_FUPA);
    unsigned* fredB = (unsigned*)(ws + G_FREDB);
    unsigned* fcoef = (unsigned*)(ws + G_FCOEF);
    unsigned* fnum  = (unsigned*)(ws + G_FNUM);
    float* uraw = ws + G_URAW;
    float* UUP  = ws + G_UUP;
    float* FFP  = ws + G_FFP;
    float* B2P  = ws + G_B2P;
    float* DP   = ws + G_DP;
    float* NUMP = ws + G_NUMP;
    float* DENP = ws + G_DENP;
    float* UPB  = ws + G_UPB;

    const int tid = threadIdx.x, bid = blockIdx.x;
    const int lane = tid & 63, wave = tid >> 6;
    const bool owner = bid < NOWN;

    // Load R row-slab into registers ONCE: rows 4*tid..+3, cols bid*32..+31.
    const float4* R4 = (const float4*)Rm;
    float4 rr[4][8];
    #pragma unroll
    for (int r = 0; r < 4; ++r)
        #pragma unroll
        for (int c = 0; c < 8; ++c)
            rr[r][c] = R4[(size_t)((tid << 2) + r)*NC4 + (bid << 3) + c];

    // ===== I1: f slab -> LDS ; FFP partial ; u_init partials (UP slot 16) ====
    if (wave == 0) {
        float4 fv = make_float4(0.f, 0.f, 0.f, 0.f);
        if (lane < 8) { fv = ((const float4*)f)[(bid << 3) + lane];
                        ((float4*)fsl)[lane] = fv; }
        float s2 = fv.x*fv.x + fv.y*fv.y + fv.z*fv.z + fv.w*fv.w;
        s2 += __shfl_xor(s2, 1, 64);
        s2 += __shfl_xor(s2, 2, 64);
        s2 += __shfl_xor(s2, 4, 64);
        if (lane == 0) astore(&FFP[bid], s2);
    }
    __syncthreads();
    {
        float uo[4];
        u_pass_row(rr, fsl, uo);
        flush4(UPB + (size_t)16*UPSLOT, uo, tid, bid);
    }
    sigA(fupA + 16*NREPA*256, bid);

    // ===== I2 (owners): reduce UP16 -> uraw[16]=Rf ; uu partial =====
    if (owner) {
        pollA(fupA + 16*NREPA*256, bid);
        const float* base = UPB + (size_t)16*UPSLOT + (size_t)bid*(NBLK*CH);
        const int r = tid & 31, q = tid >> 5;
        float s = 0.f;
        #pragma unroll
        for (int i = 0; i < 16; ++i) s += base[(q*16 + i)*CH + r];
        red2[r][q] = s;
        __syncthreads();
        if (tid < 32) {
            float u = 0.f;
            #pragma unroll
            for (int q2 = 0; q2 < 16; ++q2) u += red2[tid][q2];
            ufin32[tid] = u;
            uh[16][tid] = u;
            astore(&uraw[16*2048 + bid*CH + tid], u);
        }
        __syncthreads();
        if (wave == 0) {
            float p = (lane < 32) ? ufin32[lane]*ufin32[lane] : 0.f;
            p = sum32(p);
            if (lane == 0) astore(&UUP[bid], p);
        }
        sigB(fredB + 16*NREPB*16, bid);
    }
    pollB(fredB + 16*NREPB*16, bid);

    // ===== I3: uu+ff reduce (all, fixed order) ; y=Hf ; W0 ; u(W0) slot 0 ====
    float4 u4 = ((const float4*)(uraw + 16*2048))[tid];   // coalesced, own rows
    if (wave == 0) {
        float s = UUP[lane];          // 64 owner partials
        s = wave_sum64(s);
        if (lane == 0) misc[3] = s;
    }
    if (wave == 1) {
        float s = 0.f;
        #pragma unroll
        for (int i = 0; i < 4; ++i) s += FFP[lane + 64*i];
        s = wave_sum64(s);
        if (lane == 0) misc[2] = s;
    }
    {
        float4 acc[8];
        #pragma unroll
        for (int c = 0; c < 8; ++c) acc[c] = make_float4(0.f, 0.f, 0.f, 0.f);
        const float ua[4] = {u4.x, u4.y, u4.z, u4.w};
        #pragma unroll
        for (int r = 0; r < 4; ++r) {
            const float ut = ua[r];
            #pragma unroll
            for (int c = 0; c < 8; ++c) {
                acc[c].x -= ut*rr[r][c].x; acc[c].y -= ut*rr[r][c].y;
                acc[c].z -= ut*rr[r][c].z; acc[c].w -= ut*rr[r][c].w;
            }
        }
        y_reduce8(acc, red, ysl, wave, lane, tid);   // barriers make misc visible
        const float E = -misc[3] / (misc[2] + 1e-15f);
        float v = 0.f;
        if (tid < 32) { v = E*fsl[tid] - ysl[tid]; Wh[0][tid] = v; }
        if (wave == 0) {
            float s = (lane < 32) ? v*v : 0.f;
            s = wave_sum64(s);
            if (lane == 0) astore(&B2P[0*256 + bid], s);
        }
        __syncthreads();
        float uo[4];
        u_pass_row(rr, Wh[0], uo);
        flush4(UPB + (size_t)0*UPSLOT, uo, tid, bid);
    }
    sigA(fupA + 0*NREPA*256, bid);

    // ===== Lanczos steps j=0..15 =====
    for (int j = 0; j < LORD; ++j) {
        float* UPj = UPB + (size_t)j*UPSLOT;
        float* DPj = DP + j*(16*NOWN);
        // --- Phase 1 (owners): reduce u chunk ; dot partials vs history ---
        if (owner) {
            pollA(fupA + j*NREPA*256, bid);
            const float* base = UPj + (size_t)bid*(NBLK*CH);
            const int r = tid & 31, q = tid >> 5;
            float s = 0.f;
            #pragma unroll
            for (int i = 0; i < 16; ++i) s += base[(q*16 + i)*CH + r];
            red2[r][q] = s;
            __syncthreads();
            if (tid < 32) {
                float u = 0.f;
                #pragma unroll
                for (int q2 = 0; q2 < 16; ++q2) u += red2[tid][q2];
                ufin32[tid] = u;
                uh[j][tid] = u;
                astore(&uraw[(size_t)j*2048 + bid*CH + tid], u);
            }
            __syncthreads();
            for (int k = wave; k <= j; k += 8) {
                float p = (lane < 32) ? ufin32[lane]*uh[k][lane] : 0.f;
                p = sum32(p);
                if (lane == 0) astore(&DPj[k*NOWN + bid], p);
            }
            sigB(fredB + j*NREPB*16, bid);
        }
        pollB(fredB + j*NREPB*16, bid);

        // --- Phase 2 (all): coalesced u read (early); dots+b2; y; W_{j+1} ---
        float4 uj4 = make_float4(0.f, 0.f, 0.f, 0.f);
        if (j < LORD - 1)
            uj4 = ((const float4*)(uraw + (size_t)j*2048))[tid];
        for (int k = wave; k <= j; k += 8) {
            float s = DPj[k*NOWN + lane];     // 64 owner partials
            s = wave_sum64(s);
            if (lane == 0) dotl[k] = s;
        }
        if (wave == 1) {   // every block reduces B2P[j] identically
            float s = 0.f;
            #pragma unroll
            for (int i = 0; i < 4; ++i) s += B2P[j*256 + lane + 64*i];
            s = wave_sum64(s);
            if (lane == 0) misc[0] = s;
        }
        __syncthreads();
        const float b2j = misc[0];
        const float bj  = sqrtf(fmaxf(b2j, 1e-60f));   // ref: w/max(b,1e-30)
        if (tid == 0) {
            bh[j]   = bj;
            alph[j] = -dotl[j] / fmaxf(b2j, 1e-60f);
        }
        if (j < LORD - 1) {
            // y on RAW u (y is linear: fold 1/bj into the 32-value W update).
            float4 acc[8];
            #pragma unroll
            for (int c = 0; c < 8; ++c) acc[c] = make_float4(0.f, 0.f, 0.f, 0.f);
            const float ua[4] = {uj4.x, uj4.y, uj4.z, uj4.w};
            #pragma unroll
            for (int r = 0; r < 4; ++r) {
                const float ut = ua[r];
                #pragma unroll
                for (int c = 0; c < 8; ++c) {
                    acc[c].x -= ut*rr[r][c].x; acc[c].y -= ut*rr[r][c].y;
                    acc[c].z -= ut*rr[r][c].z; acc[c].w -= ut*rr[r][c].w;
                }
            }
            y_reduce8(acc, red, ysl, wave, lane, tid);
            const float inv = 1.0f / bj;
            // W_{j+1} = y/bj + sum_{k<=j} dot_jk/(b_j b_k^2) W_k (full reorth)
            float v = 0.f;
            if (tid < 32) {
                v = ysl[tid] * inv;
                for (int k = 0; k <= j; ++k)
                    v += (dotl[k] / (bj * bh[k] * bh[k])) * Wh[k][tid];
                Wh[j+1][tid] = v;
            }
            if (wave == 0) {
                float s = (lane < 32) ? v*v : 0.f;
                s = wave_sum64(s);
                if (lane == 0) astore(&B2P[(j+1)*256 + bid], s);
            }
            __syncthreads();
            float uo[4];
            u_pass_row(rr, Wh[j+1], uo);
            flush4(UPB + (size_t)(j+1)*UPSLOT, uo, tid, bid);
            sigA(fupA + (j+1)*NREPA*256, bid);
        } else {
            __syncthreads();   // alph[15]/bh[15] visible
            // coeffs = normF * exp(-tau*T) e0 via fp64 Taylor (block 0)
            if (bid == 0 && wave == 0) {
                double a = 0.0, bl = 0.0;
                if (lane < LORD)     a  = (double)alph[lane];
                if (lane < LORD - 1) bl = (double)bh[lane + 1];
                double bprev = __shfl_up(bl, 1, 64);
                if (lane == 0) bprev = 0.0;
                if (lane >= LORD) { a = 0.0; bl = 0.0; bprev = 0.0; }
                double v = (lane == 0) ? 1.0 : 0.0;
                double accd = v;
                for (int n = 1; n <= 30; ++n) {
                    double vm = __shfl_up(v, 1, 64);
                    if (lane == 0) vm = 0.0;
                    double vp = __shfl_down(v, 1, 64);
                    if (lane >= LORD - 1) vp = 0.0;
                    const double tv = a*v + bprev*vm + bl*vp;
                    v = tv * (-0.08 / (double)n);
                    accd += v;
                }
                if (lane < LORD)
                    astore(&coefg[lane], (float)accd * bh[0]);
            }
            __syncthreads();   // drain coef stores before flag (bid 0)
            // Replicated coef-ready flags, one word per 64B line.
            if (bid == 0 && tid < NREPB) astoreu(&fcoef[tid*16], 1u);
            if (tid == 0)
                while (aloadu(&fcoef[(bid & (NREPB-1))*16]) == 0u)
                    __builtin_amdgcn_s_sleep(2);
            __syncthreads();
        }
    }

    // ===== F1: dir slab from LDS W history ; num/den partials =====
    if (wave == 0 && lane < 16) cf[lane] = coefg[lane];
    __syncthreads();
    if (tid < 32) {
        float s = 0.f;
        #pragma unroll
        for (int l = 0; l < LORD; ++l) s += cf[l] * Wh[l][tid] / bh[l];
        dirs[tid] = s;
    }
    __syncthreads();
    if (wave == 0 && lane < 16) {
        const float4* Dp = (const float4*)Dm + (size_t)lane*NC4 + (bid << 3);
        float num = 0.f, den = 0.f;
        #pragma unroll
        for (int g = 0; g < 8; ++g) {
            const float4 dv = Dp[g];
            const float4 dr = ((const float4*)dirs)[g];
            num += dv.x*dr.x + dv.y*dr.y + dv.z*dr.z + dv.w*dr.w;
            den += dv.x*dv.x + dv.y*dv.y + dv.z*dv.z + dv.w*dv.w;
        }
        astore(&NUMP[lane*256 + bid], num);
        astore(&DENP[lane*256 + bid], den);
    }
    sigA(fnum, bid);
    // Blocks != 0 are done; only block 0 waits for all num/den partials.

    // ===== F2: block 0 reduces num/den deterministically, writes out =====
    if (bid == 0) {
        pollA(fnum, 0);
        for (int p = wave; p < 16; p += 8) {
            float n = 0.f, d = 0.f;
            #pragma unroll
            for (int i = 0; i < 4; ++i) {
                n += NUMP[p*256 + lane + 64*i];
                d += DENP[p*256 + lane + 64*i];
            }
            n = wave_sum64(n);
            d = wave_sum64(d);
            if (lane == 0) out[p] = n / (d + 1e-4f);
        }
    }
}

extern "C" void kernel_launch(void* const* d_in, const int* in_sizes, int n_in,
                              void* d_out, int out_size, void* d_ws, size_t ws_size,
                              hipStream_t stream)
{
    (void)in_sizes; (void)n_in; (void)out_size; (void)ws_size;
    const float* f  = (const float*)d_in[0];
    const float* Rm = (const float*)d_in[1];
    const float* Dm = (const float*)d_in[2];
    float* outp = (float*)d_out;
    float* ws   = (float*)d_ws;
    // Zero coef + flags (~166 KB). All rotated payload buffers are written
    // before their single read each launch.
    hipMemsetAsync(ws, 0, G_ZEND * sizeof(float), stream);
    void* args[] = { (void*)&Rm, (void*)&f, (void*)&Dm, (void*)&outp, (void*)&ws };
    hipLaunchCooperativeKernel((const void*)k_all, dim3(NBLK), dim3(NTHR),
                               args, 0, stream);
}

// Round 5
// 318.900 us; speedup vs baseline: 1.6783x; 1.6783x over previous
//
#include <hip/hip_runtime.h>
#include <math.h>

// Problem constants
#define D_FEAT 8192
#define NC4    2048          // float4 columns per R row
#define T_RES  2048
#define LORD   16

// Geometry: 256 blocks x 512 threads (1 block/CU). Block owns a 32-column slab
// of R (all 2048 rows) in registers: thread (cg=tid&7, rg=tid>>3) holds rows
// rg+64*i (i<32) of float4-column (bid*8+cg). 32 float4 = 128 regs.
// R5 FIX: __launch_bounds__(512,1) — the old ",2" acted as min-2-BLOCKS/CU,
// capping VGPRs at 128, so rr was NEVER resident (compiler re-loaded R from
// L2/LLC every pass: ~2.1 GB cache traffic/dispatch = the real bottleneck).
// With a 256-VGPR budget + asm pin, rr stays in registers.
#define NTHR 512
#define NBLK 256
#define RPT  32
#define NOWN 32              // u-reduction chunk owners (64 rows each)
#define CH   64              // rows per chunk
#define NREPA 4              // A-flag replicas (pollers = 32 owners)
#define NREPB 16             // B-flag replicas (pollers = 256 blocks)

// ---- Global workspace layout (float offsets) ----
// Zeroed region: coef + flags (~90 KB memset per launch).
#define G_COEF  0                              // 16
#define G_FUPA  16                             // 17 x NREPA x 256 partial-ready
#define G_FREDB (G_FUPA + 17*NREPA*256)        // 17 x NREPB x 16 bitmask words (line-padded)
#define G_FCOEF (G_FREDB + 17*NREPB*16)        // NREPB x 16 (1 word per line)
#define G_FNUM  (G_FCOEF + NREPB*16)           // NREPA x 256 (block 0 polls)
#define G_ZEND  (G_FNUM + NREPA*256)
// Rotated single-write-then-single-read regions (cached reads safe: caches
// invalidated at dispatch; each slot written once then read once per launch):
#define G_URAW  G_ZEND                         // 17 x 2048 reduced u (slot16 = R f)
#define G_UUP   (G_URAW + 17*2048)             // 32 |u_init|^2 owner partials
#define G_FFP   (G_UUP + 32)                   // 256 f.f partials
#define G_B2P   (G_FFP + 256)                  // 16 x 256 b2 partials (slot j)
#define G_DP    (G_B2P + 16*256)               // 16 x 16 x 32 dot owner partials
#define G_NUMP  (G_DP + 16*16*32)              // 16 x 256
#define G_DENP  (G_NUMP + 16*256)              // 16 x 256
#define G_UPB   ((G_DENP + 16*256 + 1023) & ~1023)  // 17 x NOWN*NBLK*CH u partials
#define UPSLOT  (NOWN*NBLK*CH)                 // 524288 floats = 2MB

// ---- MALL-coherent uncached ops (writes + sync polling) — validated R5-R8
__device__ __forceinline__ void astore(float* p, float v) {
    __hip_atomic_store(p, v, __ATOMIC_RELAXED, __HIP_MEMORY_SCOPE_AGENT);
}
__device__ __forceinline__ void astoreu(unsigned* p, unsigned v) {
    __hip_atomic_store(p, v, __ATOMIC_RELAXED, __HIP_MEMORY_SCOPE_AGENT);
}
__device__ __forceinline__ unsigned aloadu(const unsigned* p) {
    return __hip_atomic_load(p, __ATOMIC_RELAXED, __HIP_MEMORY_SCOPE_AGENT);
}

// Sync A (all 256 produce partials; only 32 owners consume): __syncthreads
// drains vmcnt so payload astores are at MALL before the flag stores issue.
__device__ __forceinline__ void sigA(unsigned* fl, int bid) {
    __syncthreads();
    if (threadIdx.x < NREPA) astoreu(&fl[threadIdx.x*256 + bid], 1u);
}
// Owners poll replica (bid&3): 8 owner-blocks x 64 lanes per replica — low
// fan-in (R1 lesson: 256x64 pollers on one copy saturated the fabric).
__device__ __forceinline__ void pollA(const unsigned* fl, int bid) {
    if (threadIdx.x < 64) {
        const unsigned* p = fl + (bid & (NREPA-1))*256 + 4*threadIdx.x;
        for (;;) {
            unsigned a = aloadu(p) & aloadu(p+1) & aloadu(p+2) & aloadu(p+3);
            if (__all((int)a)) break;
            __builtin_amdgcn_s_sleep(2);
        }
    }
    __syncthreads();
}

// Sync B (32 owners produce reduced u; all 256 consume): owners atomic_or
// their bit into NREPB replicated bitmask words (one per 64B line). Each
// consumer polls ONE word of replica (bid&15) -> 16 blocks x 1 lane per line.
__device__ __forceinline__ void sigB(unsigned* fl, int bid) {
    __syncthreads();   // drain reduced-u / DP / UUP stores
    if (threadIdx.x < NREPB)
        __hip_atomic_fetch_or(&fl[threadIdx.x*16], 1u << bid,
                              __ATOMIC_RELAXED, __HIP_MEMORY_SCOPE_AGENT);
}
__device__ __forceinline__ void pollB(const unsigned* fl, int bid) {
    if (threadIdx.x == 0)
        while (aloadu(&fl[(bid & (NREPB-1))*16]) != 0xFFFFFFFFu)
            __builtin_amdgcn_s_sleep(2);
    __syncthreads();
}

__device__ __forceinline__ float wave_sum64(float s) {
    #pragma unroll
    for (int m = 1; m < 64; m <<= 1) s += __shfl_xor(s, m, 64);
    return s;
}
// Reduce over lanes 0..31 (values on lanes >=32 must be 0/unused).
__device__ __forceinline__ float sum32(float s) {
    #pragma unroll
    for (int m = 1; m < 32; m <<= 1) s += __shfl_xor(s, m, 64);
    return s;
}

// slab u contribution into LDS: row t=rg+64i, d = R[t][slab] . w_slab
__device__ __forceinline__ void u_pass_lds(const float4 (&rr)[RPT],
                                           const float* wsl, float* ubuf,
                                           int rg, int cg) {
    const float4 w4 = ((const float4*)wsl)[cg];
    #pragma unroll
    for (int i = 0; i < RPT; ++i) {
        float d = rr[i].x*w4.x + rr[i].y*w4.y + rr[i].z*w4.z + rr[i].w*w4.w;
        d += __shfl_xor(d, 1, 64);
        d += __shfl_xor(d, 2, 64);
        d += __shfl_xor(d, 4, 64);
        if (cg == 0) ubuf[rg + 64*i] = d;
    }
}

// Flush 2048 partials, 64-row-chunk layout UP[t>>6][bid][t&63]: per wave-instr
// all 64 lanes hit one contiguous 256B run -> full 64B-line write packets.
__device__ __forceinline__ void flush_up(float* UP, const float* ubuf,
                                         int bid, int tid) {
    #pragma unroll
    for (int r = 0; r < 4; ++r) {
        const int t = tid + 512*r;
        astore(&UP[(size_t)(t >> 6)*(NBLK*CH) + bid*CH + (t & 63)], ubuf[t]);
    }
}

// Owner (bid<32) reduces its 64-row chunk: one contiguous 64KB streaming
// CACHED read (slot written-once this launch). Fixed order: m ascending
// within group, groups 0..7 ascending.
__device__ __forceinline__ void reduce_up64(const float* __restrict__ UP,
                                            float* udst, float (*red8)[CH],
                                            float* ufin64, float* uhrow,
                                            int bid, int tid) {
    const int r = tid & 63, bg = tid >> 6;
    const float* base = UP + (size_t)bid*(NBLK*CH);
    float s = 0.f;
    #pragma unroll
    for (int m = 0; m < 32; ++m) s += base[(bg*32 + m)*CH + r];
    red8[bg][r] = s;
    __syncthreads();
    if (tid < 64) {
        float u = 0.f;
        #pragma unroll
        for (int g = 0; g < 8; ++g) u += red8[g][tid];
        ufin64[tid] = u;
        uhrow[tid] = u;
        astore(&udst[bid*CH + tid], u);   // 64 lanes -> 256B contiguous
    }
    __syncthreads();
}

// y slab partial: acc = -sum_t u[t]*R[t, my col4] over this thread's 32 rows
__device__ __forceinline__ float4 y_pass(const float4 (&rr)[RPT],
                                         const float* u, int rg) {
    float4 acc = make_float4(0.f, 0.f, 0.f, 0.f);
    #pragma unroll
    for (int i = 0; i < RPT; ++i) {
        const float ut = u[rg + 64*i];
        acc.x -= ut*rr[i].x; acc.y -= ut*rr[i].y;
        acc.z -= ut*rr[i].z; acc.w -= ut*rr[i].w;
    }
    return acc;
}

// Reduce per-thread y partials (over rg) into ysl[32]. Fixed order everywhere.
__device__ __forceinline__ void y_reduce(float4 acc, float (*red)[8][4],
                                         float* ysl, int wave, int lane, int tid) {
    #pragma unroll
    for (int m = 8; m < 64; m <<= 1) {
        acc.x += __shfl_xor(acc.x, m, 64); acc.y += __shfl_xor(acc.y, m, 64);
        acc.z += __shfl_xor(acc.z, m, 64); acc.w += __shfl_xor(acc.w, m, 64);
    }
    if (lane < 8) {
        red[wave][lane][0] = acc.x; red[wave][lane][1] = acc.y;
        red[wave][lane][2] = acc.z; red[wave][lane][3] = acc.w;
    }
    __syncthreads();
    if (tid < 32) {
        const int g = tid >> 2, comp = tid & 3;
        float s = 0.f;
        #pragma unroll
        for (int w = 0; w < 8; ++w) s += red[w][g][comp];
        ysl[g*4 + comp] = s;
    }
    __syncthreads();
}

__global__ __launch_bounds__(NTHR, 1) void k_all(
    const float* __restrict__ Rm, const float* __restrict__ f,
    const float* __restrict__ Dm, float* __restrict__ out,
    float* __restrict__ ws)
{
    __shared__ __align__(16) float ubuf[2048];
    __shared__ float red8[8][CH];
    __shared__ float red[8][8][4];
    __shared__ float ufin64[CH];
    __shared__ float uh[17][CH];       // owner-only: chunk history for dots
    __shared__ __align__(16) float ysl[32];
    __shared__ __align__(16) float dirs[32];
    __shared__ __align__(16) float fsl[32];
    __shared__ float Wh[LORD][32];
    __shared__ float bh[LORD];
    __shared__ float alph[LORD];
    __shared__ float dotl[LORD];
    __shared__ float cf[LORD];
    __shared__ float misc[4];   // [0]=b2j  [2]=ff  [3]=uu

    float* coefg    = ws + G_COEF;
    unsigned* fupA  = (unsigned*)(ws + G_FUPA);
    unsigned* fredB = (unsigned*)(ws + G_FREDB);
    unsigned* fcoef = (unsigned*)(ws + G_FCOEF);
    unsigned* fnum  = (unsigned*)(ws + G_FNUM);
    float* uraw = ws + G_URAW;
    float* UUP  = ws + G_UUP;
    float* FFP  = ws + G_FFP;
    float* B2P  = ws + G_B2P;
    float* DP   = ws + G_DP;
    float* NUMP = ws + G_NUMP;
    float* DENP = ws + G_DENP;
    float* UPB  = ws + G_UPB;

    const int tid = threadIdx.x, bid = blockIdx.x;
    const int cg = tid & 7, rg = tid >> 3;
    const int lane = tid & 63, wave = tid >> 6;
    const bool owner = bid < NOWN;

    // Load R column-slab into registers ONCE, then PIN via opaque asm: the
    // compiler can no longer rematerialize these by re-loading from global
    // (which under the old 128-VGPR cap silently re-read 64MB of R from
    // L2/LLC in EVERY u/y pass — ~2.1 GB cache traffic per dispatch).
    const float4* R4 = (const float4*)Rm;
    float4 rr[RPT];
    #pragma unroll
    for (int i = 0; i < RPT; ++i)
        rr[i] = R4[(size_t)(rg + 64*i)*NC4 + (bid << 3) + cg];
    #pragma unroll
    for (int i = 0; i < RPT; ++i)
        asm volatile("" : "+v"(rr[i].x), "+v"(rr[i].y),
                          "+v"(rr[i].z), "+v"(rr[i].w));

    // ===== I1: f slab -> LDS ; FFP partial ; u_init partials (UP slot 16) =====
    if (wave == 0) {
        float4 fv = make_float4(0.f, 0.f, 0.f, 0.f);
        if (lane < 8) { fv = ((const float4*)f)[(bid << 3) + lane];
                        ((float4*)fsl)[lane] = fv; }
        float s2 = fv.x*fv.x + fv.y*fv.y + fv.z*fv.z + fv.w*fv.w;
        s2 += __shfl_xor(s2, 1, 64);
        s2 += __shfl_xor(s2, 2, 64);
        s2 += __shfl_xor(s2, 4, 64);
        if (lane == 0) astore(&FFP[bid], s2);
    }
    __syncthreads();
    u_pass_lds(rr, fsl, ubuf, rg, cg);
    __syncthreads();
    flush_up(UPB + (size_t)16*UPSLOT, ubuf, bid, tid);
    sigA(fupA + 16*NREPA*256, bid);

    // ===== I2 (owners): reduce UP16 -> uraw[16]=Rf ; uu partial =====
    if (owner) {
        pollA(fupA + 16*NREPA*256, bid);
        reduce_up64(UPB + (size_t)16*UPSLOT, uraw + 16*2048, red8, ufin64,
                    uh[16], bid, tid);
        if (wave == 0) {
            float p = ufin64[lane]*ufin64[lane];
            p = wave_sum64(p);
            if (lane == 0) astore(&UUP[bid], p);
        }
        sigB(fredB + 16*NREPB*16, bid);
    }
    pollB(fredB + 16*NREPB*16, bid);

    // ===== I3: uu+ff reduce (all, fixed order) ; y=Hf ; W0 ; u(W0) slot 0 =====
    if (wave == 0) {
        float s = (lane < NOWN) ? UUP[lane] : 0.f;
        s = sum32(s);
        if (lane == 0) misc[3] = s;
    }
    if (wave == 1) {
        float s = 0.f;
        #pragma unroll
        for (int i = 0; i < 4; ++i) s += FFP[lane + 64*i];
        s = wave_sum64(s);
        if (lane == 0) misc[2] = s;
    }
    #pragma unroll
    for (int r = 0; r < 4; ++r)
        ubuf[tid + 512*r] = uraw[16*2048 + tid + 512*r];
    __syncthreads();
    {
        float4 acc = y_pass(rr, ubuf, rg);
        y_reduce(acc, red, ysl, wave, lane, tid);
        const float E = -misc[3] / (misc[2] + 1e-15f);
        float v = 0.f;
        if (tid < 32) { v = E*fsl[tid] - ysl[tid]; Wh[0][tid] = v; }
        if (wave == 0) {
            float s = (lane < 32) ? v*v : 0.f;
            s = wave_sum64(s);
            if (lane == 0) astore(&B2P[0*256 + bid], s);
        }
        __syncthreads();
        u_pass_lds(rr, Wh[0], ubuf, rg, cg);
        __syncthreads();
        flush_up(UPB + (size_t)0*UPSLOT, ubuf, bid, tid);
    }
    sigA(fupA + 0*NREPA*256, bid);

    // ===== Lanczos steps j=0..15 =====
    for (int j = 0; j < LORD; ++j) {
        float* UPj = UPB + (size_t)j*UPSLOT;
        float* DPj = DP + j*(16*NOWN);
        // --- Phase 1 (owners): reduce u ; dot partials vs chunk history ---
        if (owner) {
            pollA(fupA + j*NREPA*256, bid);
            reduce_up64(UPj, uraw + (size_t)j*2048, red8, ufin64, uh[j],
                        bid, tid);
            for (int k = wave; k <= j; k += 8) {
                float p = ufin64[lane] * uh[k][lane];
                p = wave_sum64(p);
                if (lane == 0) astore(&DPj[k*NOWN + bid], p);
            }
            sigB(fredB + j*NREPB*16, bid);
        }
        pollB(fredB + j*NREPB*16, bid);

        // --- Phase 2 (all): u read; dots+b2 reduce (fixed order); y; W ---
        float tmp[4];
        if (j < LORD - 1) {
            #pragma unroll
            for (int r = 0; r < 4; ++r)
                tmp[r] = uraw[(size_t)j*2048 + tid + 512*r];
        }
        for (int k = wave; k <= j; k += 8) {
            float s = (lane < NOWN) ? DPj[k*NOWN + lane] : 0.f;
            s = sum32(s);
            if (lane == 0) dotl[k] = s;
        }
        if (wave == 1) {   // every block reduces B2P[j] identically
            float s = 0.f;
            #pragma unroll
            for (int i = 0; i < 4; ++i) s += B2P[j*256 + lane + 64*i];
            s = wave_sum64(s);
            if (lane == 0) misc[0] = s;
        }
        __syncthreads();
        const float b2j = misc[0];
        const float bj  = sqrtf(fmaxf(b2j, 1e-60f));   // ref: w/max(b,1e-30)
        if (tid == 0) {
            bh[j]   = bj;
            alph[j] = -dotl[j] / fmaxf(b2j, 1e-60f);
        }
        if (j < LORD - 1) {
            const float inv = 1.0f / bj;
            #pragma unroll
            for (int r = 0; r < 4; ++r) ubuf[tid + 512*r] = tmp[r] * inv;
            __syncthreads();
            float4 acc = y_pass(rr, ubuf, rg);
            y_reduce(acc, red, ysl, wave, lane, tid);
            // W_{j+1} = y + sum_{k<=j} dot_jk/(b_j b_k^2) W_k  (full reorth)
            float v = 0.f;
            if (tid < 32) {
                v = ysl[tid];
                for (int k = 0; k <= j; ++k)
                    v += (dotl[k] / (bj * bh[k] * bh[k])) * Wh[k][tid];
                Wh[j+1][tid] = v;
            }
            if (wave == 0) {
                float s = (lane < 32) ? v*v : 0.f;
                s = wave_sum64(s);
                if (lane == 0) astore(&B2P[(j+1)*256 + bid], s);
            }
            __syncthreads();
            u_pass_lds(rr, Wh[j+1], ubuf, rg, cg);
            __syncthreads();
            flush_up(UPB + (size_t)(j+1)*UPSLOT, ubuf, bid, tid);
            sigA(fupA + (j+1)*NREPA*256, bid);
        } else {
            __syncthreads();   // alph[15]/bh[15] visible
            // coeffs = normF * exp(-tau*T) e0 via fp64 Taylor (block 0)
            if (bid == 0 && wave == 0) {
                double a = 0.0, bl = 0.0;
                if (lane < LORD)     a  = (double)alph[lane];
                if (lane < LORD - 1) bl = (double)bh[lane + 1];
                double bprev = __shfl_up(bl, 1, 64);
                if (lane == 0) bprev = 0.0;
                if (lane >= LORD) { a = 0.0; bl = 0.0; bprev = 0.0; }
                double v = (lane == 0) ? 1.0 : 0.0;
                double accd = v;
                for (int n = 1; n <= 30; ++n) {
                    double vm = __shfl_up(v, 1, 64);
                    if (lane == 0) vm = 0.0;
                    double vp = __shfl_down(v, 1, 64);
                    if (lane >= LORD - 1) vp = 0.0;
                    const double tv = a*v + bprev*vm + bl*vp;
                    v = tv * (-0.08 / (double)n);
                    accd += v;
                }
                if (lane < LORD)
                    astore(&coefg[lane], (float)accd * bh[0]);
            }
            __syncthreads();   // drain coef stores before flag (bid 0)
            // Replicated coef-ready flags, one word per 64B line.
            if (bid == 0 && tid < NREPB) astoreu(&fcoef[tid*16], 1u);
            if (tid == 0)
                while (aloadu(&fcoef[(bid & (NREPB-1))*16]) == 0u)
                    __builtin_amdgcn_s_sleep(2);
            __syncthreads();
        }
    }

    // ===== F1: dir slab from LDS W history ; num/den partials =====
    if (wave == 0 && lane < 16) cf[lane] = coefg[lane];
    __syncthreads();
    if (tid < 32) {
        float s = 0.f;
        #pragma unroll
        for (int l = 0; l < LORD; ++l) s += cf[l] * Wh[l][tid] / bh[l];
        dirs[tid] = s;
    }
    __syncthreads();
    if (wave == 0 && lane < 16) {
        const float4* Dp = (const float4*)Dm + (size_t)lane*NC4 + (bid << 3);
        float num = 0.f, den = 0.f;
        #pragma unroll
        for (int g = 0; g < 8; ++g) {
            const float4 dv = Dp[g];
            const float4 dr = ((const float4*)dirs)[g];
            num += dv.x*dr.x + dv.y*dr.y + dv.z*dr.z + dv.w*dr.w;
            den += dv.x*dv.x + dv.y*dv.y + dv.z*dv.z + dv.w*dv.w;
        }
        astore(&NUMP[lane*256 + bid], num);
        astore(&DENP[lane*256 + bid], den);
    }
    sigA(fnum, bid);
    // Blocks != 0 are done; only block 0 waits for all num/den partials.

    // ===== F2: block 0 reduces num/den deterministically, writes out =====
    if (bid == 0) {
        pollA(fnum, 0);
        for (int p = wave; p < 16; p += 8) {
            float n = 0.f, d = 0.f;
            #pragma unroll
            for (int i = 0; i < 4; ++i) {
                n += NUMP[p*256 + lane + 64*i];
                d += DENP[p*256 + lane + 64*i];
            }
            n = wave_sum64(n);
            d = wave_sum64(d);
            if (lane == 0) out[p] = n / (d + 1e-4f);
        }
    }
}

extern "C" void kernel_launch(void* const* d_in, const int* in_sizes, int n_in,
                              void* d_out, int out_size, void* d_ws, size_t ws_size,
                              hipStream_t stream)
{
    (void)in_sizes; (void)n_in; (void)out_size; (void)ws_size;
    const float* f  = (const float*)d_in[0];
    const float* Rm = (const float*)d_in[1];
    const float* Dm = (const float*)d_in[2];
    float* outp = (float*)d_out;
    float* ws   = (float*)d_ws;
    // Zero coef + flags (~90 KB). All rotated payload buffers are written
    // before their single read each launch.
    hipMemsetAsync(ws, 0, G_ZEND * sizeof(float), stream);
    void* args[] = { (void*)&Rm, (void*)&f, (void*)&Dm, (void*)&outp, (void*)&ws };
    hipLaunchCooperativeKernel((const void*)k_all, dim3(NBLK), dim3(NTHR),
                               args, 0, stream);
}

// Round 6
// 307.175 us; speedup vs baseline: 1.7424x; 1.0382x over previous
//
#include <hip/hip_runtime.h>
#include <math.h>

// Problem constants
#define D_FEAT 8192
#define NC4    2048          // float4 columns per R row
#define T_RES  2048
#define LORD   16

// Geometry: 256 blocks x 512 threads (1 block/CU). Block owns a 32-column slab
// of R (all 2048 rows) in registers: thread (cg=tid&7, rg=tid>>3) holds rows
// rg+64*i (i<32) of float4-column (bid*8+cg). 32 float4 = 128 regs.
// R6: NOWN=64 owners (32-row chunks, halves owner MALL read); per-owner flag
// WORDS for sync B (R3's atomic_fetch_or bitmask serialized 32 RMWs on one
// line per replica ~2us/step); Taylor computed redundantly in EVERY block
// (alph/bh are block-local) -> fcoef hop deleted.
#define NTHR 512
#define NBLK 256
#define RPT  32
#define NOWN 64              // u-reduction chunk owners (32 rows each)
#define CH   32              // rows per chunk
#define NREPA 8              // A-flag replicas (pollers = 64 owners -> 8/rep)
#define NREPB 16             // B-flag replicas (pollers = 256 blocks -> 16/rep)

// ---- Global workspace layout (float offsets) ----
// Zeroed region: flags (~220 KB memset per launch).
#define G_FUPA  0                              // 17 x NREPA x 256 partial-ready
#define G_FREDB (G_FUPA + 17*NREPA*256)        // 17 x NREPB x NOWN owner words
#define G_FNUM  (G_FREDB + 17*NREPB*NOWN)      // NREPA x 256 (block 0 polls)
#define G_ZEND  (G_FNUM + NREPA*256)
// Rotated single-write-then-single-read regions (cached reads safe: caches
// invalidated at dispatch; each slot written once then read once per launch):
#define G_URAW  G_ZEND                         // 17 x 2048 reduced u (slot16 = R f)
#define G_UUP   (G_URAW + 17*2048)             // 64 |u_init|^2 owner partials
#define G_FFP   (G_UUP + 64)                   // 256 f.f partials
#define G_B2P   (G_FFP + 256)                  // 16 x 256 b2 partials (slot j)
#define G_DP    (G_B2P + 16*256)               // 16 x 16 x 64 dot owner partials
#define G_NUMP  (G_DP + 16*16*64)              // 16 x 256
#define G_DENP  (G_NUMP + 16*256)              // 16 x 256
#define G_UPB   ((G_DENP + 16*256 + 1023) & ~1023)  // 17 x UPSLOT u partials
#define UPSLOT  (NOWN*NBLK*CH)                 // 524288 floats = 2MB

// ---- MALL-coherent uncached ops (writes + sync polling) — validated R5-R8
__device__ __forceinline__ void astore(float* p, float v) {
    __hip_atomic_store(p, v, __ATOMIC_RELAXED, __HIP_MEMORY_SCOPE_AGENT);
}
__device__ __forceinline__ void astoreu(unsigned* p, unsigned v) {
    __hip_atomic_store(p, v, __ATOMIC_RELAXED, __HIP_MEMORY_SCOPE_AGENT);
}
__device__ __forceinline__ unsigned aloadu(const unsigned* p) {
    return __hip_atomic_load(p, __ATOMIC_RELAXED, __HIP_MEMORY_SCOPE_AGENT);
}

// Sync A (all 256 produce partials; 64 owners consume): __syncthreads drains
// vmcnt so payload astores are at MALL before the flag stores issue. Distinct
// words per producer -> no RMW serialization.
__device__ __forceinline__ void sigA(unsigned* fl, int bid) {
    __syncthreads();
    if (threadIdx.x < NREPA) astoreu(&fl[threadIdx.x*256 + bid], 1u);
}
// Owners poll replica (bid&7): 8 owner-blocks x 64 lanes per replica — low
// fan-in (R1 lesson: high poller fan-in saturates the fabric).
__device__ __forceinline__ void pollA(const unsigned* fl, int bid) {
    if (threadIdx.x < 64) {
        const unsigned* p = fl + (bid & (NREPA-1))*256 + 4*threadIdx.x;
        for (;;) {
            unsigned a = aloadu(p) & aloadu(p+1) & aloadu(p+2) & aloadu(p+3);
            if (__all((int)a)) break;
            __builtin_amdgcn_s_sleep(2);
        }
    }
    __syncthreads();
}

// Sync B (64 owners produce reduced u; all 256 consume): owner bid writes ITS
// WORD in each of NREPB replicas (plain stores, distinct addresses — R3's
// fetch_or serialized 32 RMWs/line at MALL). Consumer: 64 lanes poll the 64
// owner words of replica (bid&15) -> 16 consumer-blocks per replica.
__device__ __forceinline__ void sigB(unsigned* fl, int bid) {
    __syncthreads();   // drain reduced-u / DP / UUP stores
    if (threadIdx.x < NREPB) astoreu(&fl[threadIdx.x*NOWN + bid], 1u);
}
__device__ __forceinline__ void pollB(const unsigned* fl, int bid) {
    if (threadIdx.x < 64) {
        const unsigned* p = fl + (bid & (NREPB-1))*NOWN + threadIdx.x;
        while (!__all(aloadu(p) != 0u))
            __builtin_amdgcn_s_sleep(2);
    }
    __syncthreads();
}

__device__ __forceinline__ float wave_sum64(float s) {
    #pragma unroll
    for (int m = 1; m < 64; m <<= 1) s += __shfl_xor(s, m, 64);
    return s;
}
// Reduce over lanes 0..31 (values on lanes >=32 must be 0/unused).
__device__ __forceinline__ float sum32(float s) {
    #pragma unroll
    for (int m = 1; m < 32; m <<= 1) s += __shfl_xor(s, m, 64);
    return s;
}

// slab u contribution into LDS: row t=rg+64i, d = R[t][slab] . w_slab
__device__ __forceinline__ void u_pass_lds(const float4 (&rr)[RPT],
                                           const float* wsl, float* ubuf,
                                           int rg, int cg) {
    const float4 w4 = ((const float4*)wsl)[cg];
    #pragma unroll
    for (int i = 0; i < RPT; ++i) {
        float d = rr[i].x*w4.x + rr[i].y*w4.y + rr[i].z*w4.z + rr[i].w*w4.w;
        d += __shfl_xor(d, 1, 64);
        d += __shfl_xor(d, 2, 64);
        d += __shfl_xor(d, 4, 64);
        if (cg == 0) ubuf[rg + 64*i] = d;
    }
}

// Flush 2048 partials, 32-row-chunk layout UP[t>>5][bid][t&31]: per wave-instr
// each 32-lane half writes one contiguous 128B run -> full-line write packets.
__device__ __forceinline__ void flush_up(float* UP, const float* ubuf,
                                         int bid, int tid) {
    #pragma unroll
    for (int r = 0; r < 4; ++r) {
        const int t = tid + 512*r;
        astore(&UP[(size_t)(t >> 5)*(NBLK*CH) + bid*CH + (t & 31)], ubuf[t]);
    }
}

// Owner (bid<64) reduces its 32-row chunk: one contiguous 32KB streaming
// CACHED read (slot written-once this launch). Fixed order everywhere.
__device__ __forceinline__ void reduce_up32(const float* __restrict__ UP,
                                            float* udst, float (*red2)[17],
                                            float* ufin32, float* uhrow,
                                            int bid, int tid) {
    const int r = tid & 31, q = tid >> 5;   // 16 groups x 16 partials
    const float* base = UP + (size_t)bid*(NBLK*CH);
    float s = 0.f;
    #pragma unroll
    for (int i = 0; i < 16; ++i) s += base[(q*16 + i)*CH + r];
    red2[r][q] = s;
    __syncthreads();
    if (tid < 32) {
        float u = 0.f;
        #pragma unroll
        for (int q2 = 0; q2 < 16; ++q2) u += red2[tid][q2];
        ufin32[tid] = u;
        uhrow[tid] = u;
        astore(&udst[bid*CH + tid], u);   // 32 lanes -> 128B contiguous
    }
    __syncthreads();
}

// y slab partial: acc = -sum_t u[t]*R[t, my col4] over this thread's 32 rows
__device__ __forceinline__ float4 y_pass(const float4 (&rr)[RPT],
                                         const float* u, int rg) {
    float4 acc = make_float4(0.f, 0.f, 0.f, 0.f);
    #pragma unroll
    for (int i = 0; i < RPT; ++i) {
        const float ut = u[rg + 64*i];
        acc.x -= ut*rr[i].x; acc.y -= ut*rr[i].y;
        acc.z -= ut*rr[i].z; acc.w -= ut*rr[i].w;
    }
    return acc;
}

// Reduce per-thread y partials (over rg) into ysl[32]. Fixed order everywhere.
__device__ __forceinline__ void y_reduce(float4 acc, float (*red)[8][4],
                                         float* ysl, int wave, int lane, int tid) {
    #pragma unroll
    for (int m = 8; m < 64; m <<= 1) {
        acc.x += __shfl_xor(acc.x, m, 64); acc.y += __shfl_xor(acc.y, m, 64);
        acc.z += __shfl_xor(acc.z, m, 64); acc.w += __shfl_xor(acc.w, m, 64);
    }
    if (lane < 8) {
        red[wave][lane][0] = acc.x; red[wave][lane][1] = acc.y;
        red[wave][lane][2] = acc.z; red[wave][lane][3] = acc.w;
    }
    __syncthreads();
    if (tid < 32) {
        const int g = tid >> 2, comp = tid & 3;
        float s = 0.f;
        #pragma unroll
        for (int w = 0; w < 8; ++w) s += red[w][g][comp];
        ysl[g*4 + comp] = s;
    }
    __syncthreads();
}

__global__ __launch_bounds__(NTHR, 2) void k_all(
    const float* __restrict__ Rm, const float* __restrict__ f,
    const float* __restrict__ Dm, float* __restrict__ out,
    float* __restrict__ ws)
{
    __shared__ __align__(16) float ubuf[2048];
    __shared__ float red2[32][17];
    __shared__ float red[8][8][4];
    __shared__ float ufin32[32];
    __shared__ float uh[17][32];       // owner-only: chunk history for dots
    __shared__ __align__(16) float ysl[32];
    __shared__ __align__(16) float dirs[32];
    __shared__ __align__(16) float fsl[32];
    __shared__ float Wh[LORD][32];
    __shared__ float bh[LORD];
    __shared__ float alph[LORD];
    __shared__ float dotl[LORD];
    __shared__ float cf[LORD];
    __shared__ float misc[4];   // [0]=b2j  [2]=ff  [3]=uu

    unsigned* fupA  = (unsigned*)(ws + G_FUPA);
    unsigned* fredB = (unsigned*)(ws + G_FREDB);
    unsigned* fnum  = (unsigned*)(ws + G_FNUM);
    float* uraw = ws + G_URAW;
    float* UUP  = ws + G_UUP;
    float* FFP  = ws + G_FFP;
    float* B2P  = ws + G_B2P;
    float* DP   = ws + G_DP;
    float* NUMP = ws + G_NUMP;
    float* DENP = ws + G_DENP;
    float* UPB  = ws + G_UPB;

    const int tid = threadIdx.x, bid = blockIdx.x;
    const int cg = tid & 7, rg = tid >> 3;
    const int lane = tid & 63, wave = tid >> 6;
    const bool owner = bid < NOWN;

    // Load R column-slab into registers ONCE.
    const float4* R4 = (const float4*)Rm;
    float4 rr[RPT];
    #pragma unroll
    for (int i = 0; i < RPT; ++i)
        rr[i] = R4[(size_t)(rg + 64*i)*NC4 + (bid << 3) + cg];

    // ===== I1: f slab -> LDS ; FFP partial ; u_init partials (UP slot 16) =====
    if (wave == 0) {
        float4 fv = make_float4(0.f, 0.f, 0.f, 0.f);
        if (lane < 8) { fv = ((const float4*)f)[(bid << 3) + lane];
                        ((float4*)fsl)[lane] = fv; }
        float s2 = fv.x*fv.x + fv.y*fv.y + fv.z*fv.z + fv.w*fv.w;
        s2 += __shfl_xor(s2, 1, 64);
        s2 += __shfl_xor(s2, 2, 64);
        s2 += __shfl_xor(s2, 4, 64);
        if (lane == 0) astore(&FFP[bid], s2);
    }
    __syncthreads();
    u_pass_lds(rr, fsl, ubuf, rg, cg);
    __syncthreads();
    flush_up(UPB + (size_t)16*UPSLOT, ubuf, bid, tid);
    sigA(fupA + 16*NREPA*256, bid);

    // ===== I2 (owners): reduce UP16 -> uraw[16]=Rf ; uu partial =====
    if (owner) {
        pollA(fupA + 16*NREPA*256, bid);
        reduce_up32(UPB + (size_t)16*UPSLOT, uraw + 16*2048, red2, ufin32,
                    uh[16], bid, tid);
        if (wave == 0) {
            float p = (lane < 32) ? ufin32[lane]*ufin32[lane] : 0.f;
            p = sum32(p);
            if (lane == 0) astore(&UUP[bid], p);
        }
        sigB(fredB + 16*NREPB*NOWN, bid);
    }
    pollB(fredB + 16*NREPB*NOWN, bid);

    // ===== I3: uu+ff reduce (all, fixed order) ; y=Hf ; W0 ; u(W0) slot 0 =====
    if (wave == 0) {
        float s = UUP[lane];          // 64 owner partials
        s = wave_sum64(s);
        if (lane == 0) misc[3] = s;
    }
    if (wave == 1) {
        float s = 0.f;
        #pragma unroll
        for (int i = 0; i < 4; ++i) s += FFP[lane + 64*i];
        s = wave_sum64(s);
        if (lane == 0) misc[2] = s;
    }
    #pragma unroll
    for (int r = 0; r < 4; ++r)
        ubuf[tid + 512*r] = uraw[16*2048 + tid + 512*r];
    __syncthreads();
    {
        float4 acc = y_pass(rr, ubuf, rg);
        y_reduce(acc, red, ysl, wave, lane, tid);
        const float E = -misc[3] / (misc[2] + 1e-15f);
        float v = 0.f;
        if (tid < 32) { v = E*fsl[tid] - ysl[tid]; Wh[0][tid] = v; }
        if (wave == 0) {
            float s = (lane < 32) ? v*v : 0.f;
            s = wave_sum64(s);
            if (lane == 0) astore(&B2P[0*256 + bid], s);
        }
        __syncthreads();
        u_pass_lds(rr, Wh[0], ubuf, rg, cg);
        __syncthreads();
        flush_up(UPB + (size_t)0*UPSLOT, ubuf, bid, tid);
    }
    sigA(fupA + 0*NREPA*256, bid);

    // ===== Lanczos steps j=0..15 =====
    for (int j = 0; j < LORD; ++j) {
        float* UPj = UPB + (size_t)j*UPSLOT;
        float* DPj = DP + j*(16*NOWN);
        // --- Phase 1 (owners): reduce u ; dot partials vs chunk history ---
        if (owner) {
            pollA(fupA + j*NREPA*256, bid);
            reduce_up32(UPj, uraw + (size_t)j*2048, red2, ufin32, uh[j],
                        bid, tid);
            for (int k = wave; k <= j; k += 8) {
                float p = (lane < 32) ? ufin32[lane]*uh[k][lane] : 0.f;
                p = sum32(p);
                if (lane == 0) astore(&DPj[k*NOWN + bid], p);
            }
            sigB(fredB + j*NREPB*NOWN, bid);
        }
        pollB(fredB + j*NREPB*NOWN, bid);

        // --- Phase 2 (all): u read (early); dots+b2 reduce (fixed); y; W ---
        float tmp[4];
        if (j < LORD - 1) {
            #pragma unroll
            for (int r = 0; r < 4; ++r)
                tmp[r] = uraw[(size_t)j*2048 + tid + 512*r];
        }
        for (int k = wave; k <= j; k += 8) {
            float s = DPj[k*NOWN + lane];     // 64 owner partials
            s = wave_sum64(s);
            if (lane == 0) dotl[k] = s;
        }
        if (wave == 1) {   // every block reduces B2P[j] identically
            float s = 0.f;
            #pragma unroll
            for (int i = 0; i < 4; ++i) s += B2P[j*256 + lane + 64*i];
            s = wave_sum64(s);
            if (lane == 0) misc[0] = s;
        }
        __syncthreads();
        const float b2j = misc[0];
        const float bj  = sqrtf(fmaxf(b2j, 1e-60f));   // ref: w/max(b,1e-30)
        if (tid == 0) {
            bh[j]   = bj;
            alph[j] = -dotl[j] / fmaxf(b2j, 1e-60f);
        }
        if (j < LORD - 1) {
            const float inv = 1.0f / bj;
            #pragma unroll
            for (int r = 0; r < 4; ++r) ubuf[tid + 512*r] = tmp[r] * inv;
            __syncthreads();
            float4 acc = y_pass(rr, ubuf, rg);
            y_reduce(acc, red, ysl, wave, lane, tid);
            // W_{j+1} = y + sum_{k<=j} dot_jk/(b_j b_k^2) W_k  (full reorth)
            float v = 0.f;
            if (tid < 32) {
                v = ysl[tid];
                for (int k = 0; k <= j; ++k)
                    v += (dotl[k] / (bj * bh[k] * bh[k])) * Wh[k][tid];
                Wh[j+1][tid] = v;
            }
            if (wave == 0) {
                float s = (lane < 32) ? v*v : 0.f;
                s = wave_sum64(s);
                if (lane == 0) astore(&B2P[(j+1)*256 + bid], s);
            }
            __syncthreads();
            u_pass_lds(rr, Wh[j+1], ubuf, rg, cg);
            __syncthreads();
            flush_up(UPB + (size_t)(j+1)*UPSLOT, ubuf, bid, tid);
            sigA(fupA + (j+1)*NREPA*256, bid);
        } else {
            __syncthreads();   // alph[15]/bh[15] visible
            // coeffs = normF * exp(-tau*T) e0 via fp64 Taylor — computed
            // REDUNDANTLY by every block (alph/bh are block-local and
            // bit-identical): the old block0+fcoef MALL hop is deleted.
            if (wave == 0) {
                double a = 0.0, bl = 0.0;
                if (lane < LORD)     a  = (double)alph[lane];
                if (lane < LORD - 1) bl = (double)bh[lane + 1];
                double bprev = __shfl_up(bl, 1, 64);
                if (lane == 0) bprev = 0.0;
                if (lane >= LORD) { a = 0.0; bl = 0.0; bprev = 0.0; }
                double v = (lane == 0) ? 1.0 : 0.0;
                double accd = v;
                for (int n = 1; n <= 30; ++n) {
                    double vm = __shfl_up(v, 1, 64);
                    if (lane == 0) vm = 0.0;
                    double vp = __shfl_down(v, 1, 64);
                    if (lane >= LORD - 1) vp = 0.0;
                    const double tv = a*v + bprev*vm + bl*vp;
                    v = tv * (-0.08 / (double)n);
                    accd += v;
                }
                if (lane < LORD)
                    cf[lane] = (float)accd * bh[0];
            }
            __syncthreads();   // cf visible to all waves
        }
    }

    // ===== F1: dir slab from LDS W history ; num/den partials =====
    if (tid < 32) {
        float s = 0.f;
        #pragma unroll
        for (int l = 0; l < LORD; ++l) s += cf[l] * Wh[l][tid] / bh[l];
        dirs[tid] = s;
    }
    __syncthreads();
    if (wave == 0 && lane < 16) {
        const float4* Dp = (const float4*)Dm + (size_t)lane*NC4 + (bid << 3);
        float num = 0.f, den = 0.f;
        #pragma unroll
        for (int g = 0; g < 8; ++g) {
            const float4 dv = Dp[g];
            const float4 dr = ((const float4*)dirs)[g];
            num += dv.x*dr.x + dv.y*dr.y + dv.z*dr.z + dv.w*dr.w;
            den += dv.x*dv.x + dv.y*dv.y + dv.z*dv.z + dv.w*dv.w;
        }
        astore(&NUMP[lane*256 + bid], num);
        astore(&DENP[lane*256 + bid], den);
    }
    sigA(fnum, bid);
    // Blocks != 0 are done; only block 0 waits for all num/den partials.

    // ===== F2: block 0 reduces num/den deterministically, writes out =====
    if (bid == 0) {
        pollA(fnum, 0);
        for (int p = wave; p < 16; p += 8) {
            float n = 0.f, d = 0.f;
            #pragma unroll
            for (int i = 0; i < 4; ++i) {
                n += NUMP[p*256 + lane + 64*i];
                d += DENP[p*256 + lane + 64*i];
            }
            n = wave_sum64(n);
            d = wave_sum64(d);
            if (lane == 0) out[p] = n / (d + 1e-4f);
        }
    }
}

extern "C" void kernel_launch(void* const* d_in, const int* in_sizes, int n_in,
                              void* d_out, int out_size, void* d_ws, size_t ws_size,
                              hipStream_t stream)
{
    (void)in_sizes; (void)n_in; (void)out_size; (void)ws_size;
    const float* f  = (const float*)d_in[0];
    const float* Rm = (const float*)d_in[1];
    const float* Dm = (const float*)d_in[2];
    float* outp = (float*)d_out;
    float* ws   = (float*)d_ws;
    // Zero flags (~220 KB). All rotated payload buffers are written before
    // their single read each launch.
    hipMemsetAsync(ws, 0, G_ZEND * sizeof(float), stream);
    void* args[] = { (void*)&Rm, (void*)&f, (void*)&Dm, (void*)&outp, (void*)&ws };
    hipLaunchCooperativeKernel((const void*)k_all, dim3(NBLK), dim3(NTHR),
                               args, 0, stream);
}

// Round 7
// 282.432 us; speedup vs baseline: 1.8950x; 1.0876x over previous
//
#include <hip/hip_runtime.h>
#include <math.h>

// Problem constants
#define D_FEAT 8192
#define NC4    2048          // float4 columns per R row
#define T_RES  2048
#define LORD   16

// Geometry: 256 blocks x 512 threads (1 block/CU). Block owns a 32-column slab
// of R (all 2048 rows) in registers: thread (cg=tid&7, rg=tid>>3) holds rows
// rg+64*i (i<32) of float4-column (bid*8+cg). 32 float4 = 128 regs.
// R7: REGULAR launch (cooperative not needed: grid 256 <= resident capacity
// 256 CUs x 2 blocks/CU -> co-residency structurally guaranteed; all sync is
// hand-rolled flags). Fused u_pass->UP store (no ubuf staging for flush).
// Phase-2: raw-u staging overlapped with dot reduces; 1/bj folded into W.
#define NTHR 512
#define NBLK 256
#define RPT  32
#define NOWN 64              // u-reduction chunk owners (32 rows each)
#define CH   32              // rows per chunk
#define NREPA 8              // A-flag replicas (pollers = 64 owners -> 8/rep)
#define NREPB 16             // B-flag replicas (pollers = 256 blocks -> 16/rep)

// ---- Global workspace layout (float offsets) ----
// Zeroed region: flags (~220 KB memset per launch).
#define G_FUPA  0                              // 17 x NREPA x 256 partial-ready
#define G_FREDB (G_FUPA + 17*NREPA*256)        // 17 x NREPB x NOWN owner words
#define G_FNUM  (G_FREDB + 17*NREPB*NOWN)      // NREPA x 256 (block 0 polls)
#define G_ZEND  (G_FNUM + NREPA*256)
// Rotated single-write-then-single-read regions (cached reads safe: caches
// invalidated at dispatch; each slot written once then read once per launch):
#define G_URAW  G_ZEND                         // 17 x 2048 reduced u (slot16 = R f)
#define G_UUP   (G_URAW + 17*2048)             // 64 |u_init|^2 owner partials
#define G_FFP   (G_UUP + 64)                   // 256 f.f partials
#define G_B2P   (G_FFP + 256)                  // 16 x 256 b2 partials (slot j)
#define G_DP    (G_B2P + 16*256)               // 16 x 16 x 64 dot owner partials
#define G_NUMP  (G_DP + 16*16*64)              // 16 x 256
#define G_DENP  (G_NUMP + 16*256)              // 16 x 256
#define G_UPB   ((G_DENP + 16*256 + 1023) & ~1023)  // 17 x UPSLOT u partials
#define UPSLOT  (NOWN*NBLK*CH)                 // 524288 floats = 2MB

// ---- MALL-coherent uncached ops (writes + sync polling)
__device__ __forceinline__ void astore(float* p, float v) {
    __hip_atomic_store(p, v, __ATOMIC_RELAXED, __HIP_MEMORY_SCOPE_AGENT);
}
__device__ __forceinline__ void astoreu(unsigned* p, unsigned v) {
    __hip_atomic_store(p, v, __ATOMIC_RELAXED, __HIP_MEMORY_SCOPE_AGENT);
}
__device__ __forceinline__ unsigned aloadu(const unsigned* p) {
    return __hip_atomic_load(p, __ATOMIC_RELAXED, __HIP_MEMORY_SCOPE_AGENT);
}

// Sync A (all 256 produce partials; 64 owners consume): __syncthreads drains
// vmcnt so payload astores are at MALL before the flag stores issue. Distinct
// words per producer -> no RMW serialization.
__device__ __forceinline__ void sigA(unsigned* fl, int bid) {
    __syncthreads();
    if (threadIdx.x < NREPA) astoreu(&fl[threadIdx.x*256 + bid], 1u);
}
// Owners poll replica (bid&7): 8 owner-blocks x 64 lanes per replica — low
// fan-in (R1 lesson: high poller fan-in saturates the fabric).
__device__ __forceinline__ void pollA(const unsigned* fl, int bid) {
    if (threadIdx.x < 64) {
        const unsigned* p = fl + (bid & (NREPA-1))*256 + 4*threadIdx.x;
        for (;;) {
            unsigned a = aloadu(p) & aloadu(p+1) & aloadu(p+2) & aloadu(p+3);
            if (__all((int)a)) break;
            __builtin_amdgcn_s_sleep(2);
        }
    }
    __syncthreads();
}

// Sync B (64 owners produce reduced u; all 256 consume): owner bid writes ITS
// WORD in each of NREPB replicas (plain stores, distinct addresses). Consumer:
// 64 lanes poll the 64 owner words of replica (bid&15) -> 16 blocks/replica.
__device__ __forceinline__ void sigB(unsigned* fl, int bid) {
    __syncthreads();   // drain reduced-u / DP / UUP stores
    if (threadIdx.x < NREPB) astoreu(&fl[threadIdx.x*NOWN + bid], 1u);
}
__device__ __forceinline__ void pollB(const unsigned* fl, int bid) {
    if (threadIdx.x < 64) {
        const unsigned* p = fl + (bid & (NREPB-1))*NOWN + threadIdx.x;
        while (!__all(aloadu(p) != 0u))
            __builtin_amdgcn_s_sleep(2);
    }
    __syncthreads();
}

__device__ __forceinline__ float wave_sum64(float s) {
    #pragma unroll
    for (int m = 1; m < 64; m <<= 1) s += __shfl_xor(s, m, 64);
    return s;
}
// Reduce over lanes 0..31 (values on lanes >=32 must be 0/unused).
__device__ __forceinline__ float sum32(float s) {
    #pragma unroll
    for (int m = 1; m < 32; m <<= 1) s += __shfl_xor(s, m, 64);
    return s;
}

// Fused u-pass + flush: row t=rg+64i, d = R[t][slab].w_slab, 8-lane-group
// reduced; cg==0 lanes store straight to UP[t>>5][bid][t&31] (uncached).
// Store-ack latency overlaps remaining rows; no LDS staging, no barriers.
__device__ __forceinline__ void u_pass_store(const float4 (&rr)[RPT],
                                             const float* wsl, float* UP,
                                             int rg, int cg, int bid) {
    const float4 w4 = ((const float4*)wsl)[cg];
    #pragma unroll
    for (int i = 0; i < RPT; ++i) {
        float d = rr[i].x*w4.x + rr[i].y*w4.y + rr[i].z*w4.z + rr[i].w*w4.w;
        d += __shfl_xor(d, 1, 64);
        d += __shfl_xor(d, 2, 64);
        d += __shfl_xor(d, 4, 64);
        if (cg == 0) {
            const int t = rg + 64*i;
            astore(&UP[(size_t)(t >> 5)*(NBLK*CH) + bid*CH + (t & 31)], d);
        }
    }
}

// Owner (bid<64) reduces its 32-row chunk: one contiguous 32KB streaming
// CACHED read (slot written-once this launch). Fixed order everywhere.
__device__ __forceinline__ void reduce_up32(const float* __restrict__ UP,
                                            float* udst, float (*red2)[17],
                                            float* ufin32, float* uhrow,
                                            int bid, int tid) {
    const int r = tid & 31, q = tid >> 5;   // 16 groups x 16 partials
    const float* base = UP + (size_t)bid*(NBLK*CH);
    float s = 0.f;
    #pragma unroll
    for (int i = 0; i < 16; ++i) s += base[(q*16 + i)*CH + r];
    red2[r][q] = s;
    __syncthreads();
    if (tid < 32) {
        float u = 0.f;
        #pragma unroll
        for (int q2 = 0; q2 < 16; ++q2) u += red2[tid][q2];
        ufin32[tid] = u;
        uhrow[tid] = u;
        astore(&udst[bid*CH + tid], u);   // 32 lanes -> 128B contiguous
    }
    __syncthreads();
}

// y slab partial: acc = -sum_t u[t]*R[t, my col4] over this thread's 32 rows
__device__ __forceinline__ float4 y_pass(const float4 (&rr)[RPT],
                                         const float* u, int rg) {
    float4 acc = make_float4(0.f, 0.f, 0.f, 0.f);
    #pragma unroll
    for (int i = 0; i < RPT; ++i) {
        const float ut = u[rg + 64*i];
        acc.x -= ut*rr[i].x; acc.y -= ut*rr[i].y;
        acc.z -= ut*rr[i].z; acc.w -= ut*rr[i].w;
    }
    return acc;
}

// Reduce per-thread y partials (over rg) into ysl[32]. Fixed order everywhere.
__device__ __forceinline__ void y_reduce(float4 acc, float (*red)[8][4],
                                         float* ysl, int wave, int lane, int tid) {
    #pragma unroll
    for (int m = 8; m < 64; m <<= 1) {
        acc.x += __shfl_xor(acc.x, m, 64); acc.y += __shfl_xor(acc.y, m, 64);
        acc.z += __shfl_xor(acc.z, m, 64); acc.w += __shfl_xor(acc.w, m, 64);
    }
    if (lane < 8) {
        red[wave][lane][0] = acc.x; red[wave][lane][1] = acc.y;
        red[wave][lane][2] = acc.z; red[wave][lane][3] = acc.w;
    }
    __syncthreads();
    if (tid < 32) {
        const int g = tid >> 2, comp = tid & 3;
        float s = 0.f;
        #pragma unroll
        for (int w = 0; w < 8; ++w) s += red[w][g][comp];
        ysl[g*4 + comp] = s;
    }
    __syncthreads();
}

__global__ __launch_bounds__(NTHR, 2) void k_all(
    const float* __restrict__ Rm, const float* __restrict__ f,
    const float* __restrict__ Dm, float* __restrict__ out,
    float* __restrict__ ws)
{
    __shared__ __align__(16) float ubuf[2048];
    __shared__ float red2[32][17];
    __shared__ float red[8][8][4];
    __shared__ float ufin32[32];
    __shared__ float uh[17][32];       // owner-only: chunk history for dots
    __shared__ __align__(16) float ysl[32];
    __shared__ __align__(16) float dirs[32];
    __shared__ __align__(16) float fsl[32];
    __shared__ float Wh[LORD][32];
    __shared__ float bh[LORD];
    __shared__ float alph[LORD];
    __shared__ float dotl[LORD];
    __shared__ float cf[LORD];
    __shared__ float misc[4];   // [0]=b2j  [2]=ff  [3]=uu

    unsigned* fupA  = (unsigned*)(ws + G_FUPA);
    unsigned* fredB = (unsigned*)(ws + G_FREDB);
    unsigned* fnum  = (unsigned*)(ws + G_FNUM);
    float* uraw = ws + G_URAW;
    float* UUP  = ws + G_UUP;
    float* FFP  = ws + G_FFP;
    float* B2P  = ws + G_B2P;
    float* DP   = ws + G_DP;
    float* NUMP = ws + G_NUMP;
    float* DENP = ws + G_DENP;
    float* UPB  = ws + G_UPB;

    const int tid = threadIdx.x, bid = blockIdx.x;
    const int cg = tid & 7, rg = tid >> 3;
    const int lane = tid & 63, wave = tid >> 6;
    const bool owner = bid < NOWN;

    // Load R column-slab into registers ONCE.
    const float4* R4 = (const float4*)Rm;
    float4 rr[RPT];
    #pragma unroll
    for (int i = 0; i < RPT; ++i)
        rr[i] = R4[(size_t)(rg + 64*i)*NC4 + (bid << 3) + cg];

    // ===== I1: f slab -> LDS ; FFP partial ; u_init partials (UP slot 16) =====
    if (wave == 0) {
        float4 fv = make_float4(0.f, 0.f, 0.f, 0.f);
        if (lane < 8) { fv = ((const float4*)f)[(bid << 3) + lane];
                        ((float4*)fsl)[lane] = fv; }
        float s2 = fv.x*fv.x + fv.y*fv.y + fv.z*fv.z + fv.w*fv.w;
        s2 += __shfl_xor(s2, 1, 64);
        s2 += __shfl_xor(s2, 2, 64);
        s2 += __shfl_xor(s2, 4, 64);
        if (lane == 0) astore(&FFP[bid], s2);
    }
    __syncthreads();
    u_pass_store(rr, fsl, UPB + (size_t)16*UPSLOT, rg, cg, bid);
    sigA(fupA + 16*NREPA*256, bid);

    // ===== I2 (owners): reduce UP16 -> uraw[16]=Rf ; uu partial =====
    if (owner) {
        pollA(fupA + 16*NREPA*256, bid);
        reduce_up32(UPB + (size_t)16*UPSLOT, uraw + 16*2048, red2, ufin32,
                    uh[16], bid, tid);
        if (wave == 0) {
            float p = (lane < 32) ? ufin32[lane]*ufin32[lane] : 0.f;
            p = sum32(p);
            if (lane == 0) astore(&UUP[bid], p);
        }
        sigB(fredB + 16*NREPB*NOWN, bid);
    }
    pollB(fredB + 16*NREPB*NOWN, bid);

    // ===== I3: uu+ff reduce (all, fixed order) ; y=Hf ; W0 ; u(W0) slot 0 =====
    #pragma unroll
    for (int r = 0; r < 4; ++r)
        ubuf[tid + 512*r] = uraw[16*2048 + tid + 512*r];
    if (wave == 0) {
        float s = UUP[lane];          // 64 owner partials
        s = wave_sum64(s);
        if (lane == 0) misc[3] = s;
    }
    if (wave == 1) {
        float s = 0.f;
        #pragma unroll
        for (int i = 0; i < 4; ++i) s += FFP[lane + 64*i];
        s = wave_sum64(s);
        if (lane == 0) misc[2] = s;
    }
    __syncthreads();
    {
        float4 acc = y_pass(rr, ubuf, rg);
        y_reduce(acc, red, ysl, wave, lane, tid);
        const float E = -misc[3] / (misc[2] + 1e-15f);
        float v = 0.f;
        if (tid < 32) { v = E*fsl[tid] - ysl[tid]; Wh[0][tid] = v; }
        if (wave == 0) {
            float s = (lane < 32) ? v*v : 0.f;
            s = wave_sum64(s);
            if (lane == 0) astore(&B2P[0*256 + bid], s);
        }
        __syncthreads();
        u_pass_store(rr, Wh[0], UPB + (size_t)0*UPSLOT, rg, cg, bid);
    }
    sigA(fupA + 0*NREPA*256, bid);

    // ===== Lanczos steps j=0..15 =====
    for (int j = 0; j < LORD; ++j) {
        float* UPj = UPB + (size_t)j*UPSLOT;
        float* DPj = DP + j*(16*NOWN);
        // --- Phase 1 (owners): reduce u ; dot partials vs chunk history ---
        if (owner) {
            pollA(fupA + j*NREPA*256, bid);
            reduce_up32(UPj, uraw + (size_t)j*2048, red2, ufin32, uh[j],
                        bid, tid);
            for (int k = wave; k <= j; k += 8) {
                float p = (lane < 32) ? ufin32[lane]*uh[k][lane] : 0.f;
                p = sum32(p);
                if (lane == 0) astore(&DPj[k*NOWN + bid], p);
            }
            sigB(fredB + j*NREPB*NOWN, bid);
        }
        pollB(fredB + j*NREPB*NOWN, bid);

        // --- Phase 2 (all): RAW u -> ubuf immediately (loads overlap the dot
        // and b2 reduces); one barrier covers ubuf+dotl+misc; 1/bj folded
        // into the 32-value W update (y is linear in u). ---
        if (j < LORD - 1) {
            #pragma unroll
            for (int r = 0; r < 4; ++r)
                ubuf[tid + 512*r] = uraw[(size_t)j*2048 + tid + 512*r];
        }
        for (int k = wave; k <= j; k += 8) {
            float s = DPj[k*NOWN + lane];     // 64 owner partials
            s = wave_sum64(s);
            if (lane == 0) dotl[k] = s;
        }
        if (wave == 1) {   // every block reduces B2P[j] identically
            float s = 0.f;
            #pragma unroll
            for (int i = 0; i < 4; ++i) s += B2P[j*256 + lane + 64*i];
            s = wave_sum64(s);
            if (lane == 0) misc[0] = s;
        }
        __syncthreads();
        const float b2j = misc[0];
        const float bj  = sqrtf(fmaxf(b2j, 1e-60f));   // ref: w/max(b,1e-30)
        if (tid == 0) {
            bh[j]   = bj;
            alph[j] = -dotl[j] / fmaxf(b2j, 1e-60f);
        }
        if (j < LORD - 1) {
            float4 acc = y_pass(rr, ubuf, rg);   // RAW u
            y_reduce(acc, red, ysl, wave, lane, tid);
            const float inv = 1.0f / bj;
            // W_{j+1} = y/bj + sum_{k<=j} dot_jk/(b_j b_k^2) W_k (full reorth)
            float v = 0.f;
            if (tid < 32) {
                v = ysl[tid] * inv;
                for (int k = 0; k <= j; ++k)
                    v += (dotl[k] / (bj * bh[k] * bh[k])) * Wh[k][tid];
                Wh[j+1][tid] = v;
            }
            if (wave == 0) {
                float s = (lane < 32) ? v*v : 0.f;
                s = wave_sum64(s);
                if (lane == 0) astore(&B2P[(j+1)*256 + bid], s);
            }
            __syncthreads();
            u_pass_store(rr, Wh[j+1], UPB + (size_t)(j+1)*UPSLOT, rg, cg, bid);
            sigA(fupA + (j+1)*NREPA*256, bid);
        } else {
            __syncthreads();   // alph[15]/bh[15] visible
            // coeffs = normF * exp(-tau*T) e0 via fp64 Taylor — computed
            // REDUNDANTLY by every block (alph/bh are block-local and
            // bit-identical): no MALL hop.
            if (wave == 0) {
                double a = 0.0, bl = 0.0;
                if (lane < LORD)     a  = (double)alph[lane];
                if (lane < LORD - 1) bl = (double)bh[lane + 1];
                double bprev = __shfl_up(bl, 1, 64);
                if (lane == 0) bprev = 0.0;
                if (lane >= LORD) { a = 0.0; bl = 0.0; bprev = 0.0; }
                double v = (lane == 0) ? 1.0 : 0.0;
                double accd = v;
                for (int n = 1; n <= 30; ++n) {
                    double vm = __shfl_up(v, 1, 64);
                    if (lane == 0) vm = 0.0;
                    double vp = __shfl_down(v, 1, 64);
                    if (lane >= LORD - 1) vp = 0.0;
                    const double tv = a*v + bprev*vm + bl*vp;
                    v = tv * (-0.08 / (double)n);
                    accd += v;
                }
                if (lane < LORD)
                    cf[lane] = (float)accd * bh[0];
            }
            __syncthreads();   // cf visible to all waves
        }
    }

    // ===== F1: dir slab from LDS W history ; num/den partials =====
    if (tid < 32) {
        float s = 0.f;
        #pragma unroll
        for (int l = 0; l < LORD; ++l) s += cf[l] * Wh[l][tid] / bh[l];
        dirs[tid] = s;
    }
    __syncthreads();
    if (wave == 0 && lane < 16) {
        const float4* Dp = (const float4*)Dm + (size_t)lane*NC4 + (bid << 3);
        float num = 0.f, den = 0.f;
        #pragma unroll
        for (int g = 0; g < 8; ++g) {
            const float4 dv = Dp[g];
            const float4 dr = ((const float4*)dirs)[g];
            num += dv.x*dr.x + dv.y*dr.y + dv.z*dr.z + dv.w*dr.w;
            den += dv.x*dv.x + dv.y*dv.y + dv.z*dv.z + dv.w*dv.w;
        }
        astore(&NUMP[lane*256 + bid], num);
        astore(&DENP[lane*256 + bid], den);
    }
    sigA(fnum, bid);
    // Blocks != 0 are done; only block 0 waits for all num/den partials.

    // ===== F2: block 0 reduces num/den deterministically, writes out =====
    if (bid == 0) {
        pollA(fnum, 0);
        for (int p = wave; p < 16; p += 8) {
            float n = 0.f, d = 0.f;
            #pragma unroll
            for (int i = 0; i < 4; ++i) {
                n += NUMP[p*256 + lane + 64*i];
                d += DENP[p*256 + lane + 64*i];
            }
            n = wave_sum64(n);
            d = wave_sum64(d);
            if (lane == 0) out[p] = n / (d + 1e-4f);
        }
    }
}

extern "C" void kernel_launch(void* const* d_in, const int* in_sizes, int n_in,
                              void* d_out, int out_size, void* d_ws, size_t ws_size,
                              hipStream_t stream)
{
    (void)in_sizes; (void)n_in; (void)out_size; (void)ws_size;
    const float* f  = (const float*)d_in[0];
    const float* Rm = (const float*)d_in[1];
    const float* Dm = (const float*)d_in[2];
    float* outp = (float*)d_out;
    float* ws   = (float*)d_ws;
    // Zero flags (~220 KB). All rotated payload buffers are written before
    // their single read each launch.
    hipMemsetAsync(ws, 0, G_ZEND * sizeof(float), stream);
    // REGULAR launch: grid (256 blocks, 1-2/CU) <= resident capacity of the
    // 256-CU device, so all blocks are co-resident without the cooperative
    // API; all inter-block sync is hand-rolled flag-based. Cooperative launch
    // overhead was the prime suspect for the constant ~95us JSON-vs-kernel
    // duration gap across R0-R6.
    hipLaunchKernelGGL(k_all, dim3(NBLK), dim3(NTHR), 0, stream,
                       Rm, f, Dm, outp, ws);
}